// Round 8
// baseline (737.872 us; speedup 1.0000x reference)
//
#include <hip/hip_runtime.h>

#define TSTEPS 128
#define NIN 24
#define HD 128
#define BT 16
#define NBLK 128     // 2048 / BT
#define NTH 1024     // 16 waves: 0-7 = layer-0 role, 8-15 = layer-1 role

// LDS geometry (units: _Float16 elements)
// h panels: [batch 16][hidden 128], row stride RS=136 (16B-aligned rows).
#define RS    136
#define SLOT  (BT*RS)          // 2176
#define H1B   (2*SLOT)         // h1 double buffer after h0 double buffer
#define HPAN  (4*SLOT)         // total h-panel elements
// WG=1 (whh1 from global/L2): only h panels in LDS, but request 84 KiB to
// force 1 block/CU -> 128 blocks on 128 distinct CUs.
#define DYN_WG 86016
// WG=0 fallback: round-6 layout with whh1 LDS panel after the h panels.
#define W1B   HPAN
#define SM_ELTS_LDS (W1B + 65536)
#define DYN_LDSPAN (SM_ELTS_LDS*2)     // 148480 B

#define WS_NEED (512*128*2)            // 128 KiB fragment-ordered f16 whh1

typedef _Float16 half8  __attribute__((ext_vector_type(8)));
typedef _Float16 half4v __attribute__((ext_vector_type(4)));
typedef float    floatx4 __attribute__((ext_vector_type(4)));

__device__ __forceinline__ float sigf(float x) {
    return __builtin_amdgcn_rcpf(1.0f + __expf(-x));
}
__device__ __forceinline__ float tanh_f(float x) {
    return 1.0f - 2.0f * __builtin_amdgcn_rcpf(1.0f + __expf(2.0f * x));
}

__device__ __forceinline__ half8 ldw8(const float* p) {
    const float4* q = (const float4*)p;
    float4 a = q[0], b = q[1];
    half8 r;
    r[0] = (_Float16)a.x; r[1] = (_Float16)a.y; r[2] = (_Float16)a.z; r[3] = (_Float16)a.w;
    r[4] = (_Float16)b.x; r[5] = (_Float16)b.y; r[6] = (_Float16)b.z; r[7] = (_Float16)b.w;
    return r;
}

// LDS-only barrier: drain own ds ops, sync, don't drain vmcnt — global
// loads (x prefetch, whh1 fragment prefetch) span barriers, T4-style.
__device__ __forceinline__ void barrier_lgkm() {
    asm volatile("s_waitcnt lgkmcnt(0)" ::: "memory");
    __builtin_amdgcn_s_barrier();
    __builtin_amdgcn_sched_barrier(0);
}

// =====================================================================
// aux kernel: Whh1 f32 [512][128] -> ws, f16 in MFMA A-fragment order:
// frag (hw_,tI,kk) at (hw_*16 + tI*4 + kk)*512 + (qd*16+nn)*8 + e
// (identical layout to the verified LDS panel).
// =====================================================================
__global__ __launch_bounds__(256)
void wcvt(const float* __restrict__ Whh1, _Float16* __restrict__ wsw)
{
    int i = blockIdx.x * 256 + threadIdx.x;   // 0..16383, 4 f32 each
    if (i >= 512 * 32) return;
    int g  = i >> 5;
    int k0 = (i & 31) << 2;
    float4 v = *(const float4*)(Whh1 + g * HD + k0);
    half4v h; h[0] = (_Float16)v.x; h[1] = (_Float16)v.y;
              h[2] = (_Float16)v.z; h[3] = (_Float16)v.w;
    int dst = ((((g >> 4) & 7) * 16) + (g >> 7) * 4 + (k0 >> 5)) * 512
            + (((k0 >> 3) & 3) * 16 + (g & 15)) * 8 + (k0 & 7);
    *(half4v*)&wsw[dst] = h;
}

// =====================================================================
// Fused 2-layer LSTM, one block per 16-row batch tile, wave-role split
// (waves 0-7 = layer 0, waves 8-15 = layer 1), round-6 schedule:
// iter t computes layer0 step t and layer1 step t-1 off one barrier.
// WG=1: whh1 fragments stream from a shared 128 KB L2-resident global
//       buffer on the (idle) vmem pipe, double-buffered in 32 VGPRs,
//       groups 0/1 prefetched pre-barrier — removes 57% of the LDS
//       traffic that capped round 6.
// WG=0: verified round-6 whh1-in-LDS fallback.
// Transposed MFMA orientation (A=weights, B=h^T); layer-0 bias folded
// into the x-MFMA via a constant-1 x column; h-writes are ds_write_b64.
// =====================================================================
template<int WG>
__global__ __launch_bounds__(NTH, 4)
void lstm2_fused(const float* __restrict__ x,
                 const float* __restrict__ Wih0, const float* __restrict__ Whh0,
                 const float* __restrict__ bih0, const float* __restrict__ bhh0,
                 const float* __restrict__ Wih1, const float* __restrict__ Whh1,
                 const float* __restrict__ bih1, const float* __restrict__ bhh1,
                 const float* __restrict__ Wfc,  const float* __restrict__ bfc,
                 float* __restrict__ out, const _Float16* __restrict__ wsw)
{
    extern __shared__ __align__(16) _Float16 SM[];

    const int tid = threadIdx.x;
    const int blk = blockIdx.x;
    const int wv  = tid >> 6;
    const int ln  = tid & 63;
    const int qd  = ln >> 4;
    const int nn  = ln & 15;
    const int b0  = blk * BT;

    const half8 z8 = {0, 0, 0, 0, 0, 0, 0, 0};
    const floatx4 zf4 = {0.f, 0.f, 0.f, 0.f};

    // ---- zero h panels (state -1 reads as 0) ----
    for (int i = tid * 8; i < HPAN; i += NTH * 8) *(half8*)&SM[i] = z8;
    if constexpr (WG == 0) {
        // stage whh1 -> LDS panel (round-6 fallback)
        for (int i = tid; i < 512 * 32; i += NTH) {
            int g  = i >> 5;
            int k0 = (i & 31) << 2;
            float4 v = *(const float4*)(Whh1 + g * HD + k0);
            half4v h; h[0] = (_Float16)v.x; h[1] = (_Float16)v.y;
                      h[2] = (_Float16)v.z; h[3] = (_Float16)v.w;
            int dst = W1B + ((((g >> 4) & 7) * 16) + (g >> 7) * 4 + (k0 >> 5)) * 512
                          + (((k0 >> 3) & 3) * 16 + (g & 15)) * 8 + (k0 & 7);
            *(half4v*)&SM[dst] = h;
        }
    }

    if (wv < 8) {
        // ================= ROLE L0: layer 0, hidden cols wv*16..+16 =================
        const int hw_  = wv;
        const int hcol = hw_ * 16 + qd * 4;

        half8 wih0[4];           // bias folded at qd==3 via constant-1 x col
        half8 whh0[4][4];
#pragma unroll
        for (int tI = 0; tI < 4; ++tI) {
            int g = tI * HD + hw_ * 16 + nn;
            if (qd < 3) {
                wih0[tI] = ldw8(Wih0 + g * NIN + qd * 8);
            } else {
                wih0[tI] = z8;
                wih0[tI][0] = (_Float16)(bih0[g] + bhh0[g]);
            }
#pragma unroll
            for (int kk = 0; kk < 4; ++kk)
                whh0[tI][kk] = ldw8(Whh0 + g * HD + kk * 32 + qd * 8);
        }

        const float* xrow = x + (size_t)(b0 + nn) * (TSTEPS * NIN) + (qd < 3 ? qd * 8 : 0);
        float4 pf0 = *(const float4*)(xrow);
        float4 pf1 = *(const float4*)(xrow + 4);

        float cs0[4] = {0.f, 0.f, 0.f, 0.f};

        __syncthreads();   // barrier #0: zeros (+ panel) staged

        // ---- iter 0: h0[0] (h0[-1]=0 -> only x MFMA) ----
        {
            half8 ax;
            if (qd < 3) {
                ax[0] = (_Float16)pf0.x; ax[1] = (_Float16)pf0.y; ax[2] = (_Float16)pf0.z; ax[3] = (_Float16)pf0.w;
                ax[4] = (_Float16)pf1.x; ax[5] = (_Float16)pf1.y; ax[6] = (_Float16)pf1.z; ax[7] = (_Float16)pf1.w;
            } else {
                ax = z8; ax[0] = (_Float16)1.0f;
            }
            pf0 = *(const float4*)(xrow + NIN);
            pf1 = *(const float4*)(xrow + NIN + 4);

            floatx4 acc0[4];
#pragma unroll
            for (int tI = 0; tI < 4; ++tI)
                acc0[tI] = __builtin_amdgcn_mfma_f32_16x16x32_f16(wih0[tI], ax, zf4, 0, 0, 0);

            half4v hw;
#pragma unroll
            for (int r = 0; r < 4; ++r) {
                float iv = sigf(acc0[0][r]);
                float gv = tanh_f(acc0[2][r]);
                float ov = sigf(acc0[3][r]);
                float cn = iv * gv;
                cs0[r] = cn;
                hw[r] = (_Float16)(ov * tanh_f(cn));
            }
            *(half4v*)&SM[0 * SLOT + nn * RS + hcol] = hw;   // h0[0] -> slot 0
        }

#pragma unroll 1
        for (int t = 1; t < TSTEPS; ++t) {
            barrier_lgkm();   // barrier #t

            half8 ax;
            if (qd < 3) {
                ax[0] = (_Float16)pf0.x; ax[1] = (_Float16)pf0.y; ax[2] = (_Float16)pf0.z; ax[3] = (_Float16)pf0.w;
                ax[4] = (_Float16)pf1.x; ax[5] = (_Float16)pf1.y; ax[6] = (_Float16)pf1.z; ax[7] = (_Float16)pf1.w;
            } else {
                ax = z8; ax[0] = (_Float16)1.0f;
            }
            {
                const int tn = (t < TSTEPS - 1) ? t + 1 : TSTEPS - 1;
                pf0 = *(const float4*)(xrow + (size_t)tn * NIN);
                pf1 = *(const float4*)(xrow + (size_t)tn * NIN + 4);
            }

            const int h0r = ((t - 1) & 1) * SLOT;
            const int h0w = (t & 1) * SLOT;

            floatx4 acc0[4];
#pragma unroll
            for (int tI = 0; tI < 4; ++tI)
                acc0[tI] = __builtin_amdgcn_mfma_f32_16x16x32_f16(wih0[tI], ax, zf4, 0, 0, 0);

            __builtin_amdgcn_s_setprio(1);
#pragma unroll
            for (int kk = 0; kk < 4; ++kk) {
                const half8 ah = *(const half8*)&SM[h0r + nn * RS + kk * 32 + qd * 8];
#pragma unroll
                for (int tI = 0; tI < 4; ++tI)
                    acc0[tI] = __builtin_amdgcn_mfma_f32_16x16x32_f16(whh0[tI][kk], ah, acc0[tI], 0, 0, 0);
            }
            __builtin_amdgcn_s_setprio(0);

            half4v hw;
#pragma unroll
            for (int r = 0; r < 4; ++r) {
                float iv = sigf(acc0[0][r]);
                float fv = sigf(acc0[1][r]);
                float gv = tanh_f(acc0[2][r]);
                float ov = sigf(acc0[3][r]);
                float cn = fv * cs0[r] + iv * gv;
                cs0[r] = cn;
                hw[r] = (_Float16)(ov * tanh_f(cn));
            }
            *(half4v*)&SM[h0w + nn * RS + hcol] = hw;
        }

        barrier_lgkm();   // barrier #128 (publishes h0[127])
        barrier_lgkm();   // barrier #129 (waits for L1's h1[127])
    } else {
        // ================= ROLE L1: layer 1, hidden cols (wv-8)*16..+16 =================
        const int hw_  = wv - 8;
        const int hcol = hw_ * 16 + qd * 4;

        floatx4 bias1[4];
        half8 wih1[4][4];
#pragma unroll
        for (int tI = 0; tI < 4; ++tI) {
#pragma unroll
            for (int r = 0; r < 4; ++r)
                bias1[tI][r] = bih1[tI * HD + hcol + r] + bhh1[tI * HD + hcol + r];
            int g = tI * HD + hw_ * 16 + nn;
#pragma unroll
            for (int kk = 0; kk < 4; ++kk)
                wih1[tI][kk] = ldw8(Wih1 + g * HD + kk * 32 + qd * 8);
        }

        // WG=1: this wave's 16 whh1 fragments in global (L2-resident)
        const _Float16* w1g = (WG == 1) ? (wsw + hw_ * 8192 + ln * 8) : nullptr;
        const int w1base = W1B + hw_ * 8192 + ln * 8;   // WG=0 LDS panel

        half8 wS0[4], wS1[4];    // double-buffered fragment staging (32 VGPRs)
        auto ldw1 = [&](half8* buf, int kk) {
#pragma unroll
            for (int tI = 0; tI < 4; ++tI)
                buf[tI] = *(const half8*)(w1g + (tI * 4 + kk) * 512);
        };

        float cs1[4] = {0.f, 0.f, 0.f, 0.f};

        __syncthreads();   // barrier #0

        if constexpr (WG == 1) { ldw1(wS0, 0); ldw1(wS1, 1); }   // prefetch iter-1 groups

        // loop t = 1..128: t<=127 computes h1[t-1]; t==128 is the epilogue
        // (h0[127] slot 1, h1[126] slot 0) — same slot formulas.
#pragma unroll 1
        for (int t = 1; t <= TSTEPS; ++t) {
            barrier_lgkm();   // barrier #t: h0[t-1], h1[t-2] visible

            const int h0r = ((t - 1) & 1) * SLOT;
            const int h1r = H1B + (t & 1) * SLOT;            // h1[t-2]
            const int h1w = H1B + ((t & 1) ^ 1) * SLOT;      // h1[t-1]

            floatx4 acc1[4];
#pragma unroll
            for (int tI = 0; tI < 4; ++tI) acc1[tI] = bias1[tI];

            __builtin_amdgcn_s_setprio(1);
#pragma unroll
            for (int kk = 0; kk < 4; ++kk) {
                const half8 ah = *(const half8*)&SM[h0r + nn * RS + kk * 32 + qd * 8];
#pragma unroll
                for (int tI = 0; tI < 4; ++tI)
                    acc1[tI] = __builtin_amdgcn_mfma_f32_16x16x32_f16(wih1[tI][kk], ah, acc1[tI], 0, 0, 0);
            }
#pragma unroll
            for (int kk = 0; kk < 4; ++kk) {
                const half8 a2 = *(const half8*)&SM[h1r + nn * RS + kk * 32 + qd * 8];
                if constexpr (WG == 1) {
                    const half8* wb = (kk & 1) ? wS1 : wS0;
#pragma unroll
                    for (int tI = 0; tI < 4; ++tI)
                        acc1[tI] = __builtin_amdgcn_mfma_f32_16x16x32_f16(wb[tI], a2, acc1[tI], 0, 0, 0);
                    if (kk == 0) ldw1(wS0, 2);   // refill freed buffer
                    if (kk == 1) ldw1(wS1, 3);
                } else {
#pragma unroll
                    for (int tI = 0; tI < 4; ++tI) {
                        const half8 w1 = *(const half8*)&SM[w1base + (tI * 4 + kk) * 512];
                        acc1[tI] = __builtin_amdgcn_mfma_f32_16x16x32_f16(w1, a2, acc1[tI], 0, 0, 0);
                    }
                }
            }
            __builtin_amdgcn_s_setprio(0);

            half4v hw;
#pragma unroll
            for (int r = 0; r < 4; ++r) {
                float iv = sigf(acc1[0][r]);
                float fv = sigf(acc1[1][r]);
                float gv = tanh_f(acc1[2][r]);
                float ov = sigf(acc1[3][r]);
                float cn = fv * cs1[r] + iv * gv;
                cs1[r] = cn;
                hw[r] = (_Float16)(ov * tanh_f(cn));
            }
            *(half4v*)&SM[h1w + nn * RS + hcol] = hw;

            if constexpr (WG == 1) {
                if (t < TSTEPS) { ldw1(wS0, 0); ldw1(wS1, 1); }   // pre-barrier prefetch
            }
        }

        barrier_lgkm();   // barrier #129: publish h1[127]
    }

    // =============== FC head: h1[127] in h1 slot 1 (first 512 threads) ===============
    if (tid < 512) {
        int b = tid >> 5, sub = tid & 31;
        const _Float16* hp = &SM[H1B + SLOT + b * RS + sub * 4];
        const float4 wv4 = *(const float4*)(Wfc + sub * 4);
        float s = (float)hp[0] * wv4.x + (float)hp[1] * wv4.y
                + (float)hp[2] * wv4.z + (float)hp[3] * wv4.w;
        s += __shfl_down(s, 16, 32);
        s += __shfl_down(s, 8, 32);
        s += __shfl_down(s, 4, 32);
        s += __shfl_down(s, 2, 32);
        s += __shfl_down(s, 1, 32);
        if (sub == 0) out[b0 + b] = s + bfc[0];
    }
}

extern "C" void kernel_launch(void* const* d_in, const int* in_sizes, int n_in,
                              void* d_out, int out_size, void* d_ws, size_t ws_size,
                              hipStream_t stream) {
    static bool attr_set = false;
    if (!attr_set) {
        hipFuncSetAttribute(reinterpret_cast<const void*>(&lstm2_fused<1>),
                            hipFuncAttributeMaxDynamicSharedMemorySize, DYN_WG);
        hipFuncSetAttribute(reinterpret_cast<const void*>(&lstm2_fused<0>),
                            hipFuncAttributeMaxDynamicSharedMemorySize, DYN_LDSPAN);
        attr_set = true;
    }
    const float* x    = (const float*)d_in[0];
    const float* Wih0 = (const float*)d_in[1];
    const float* Whh0 = (const float*)d_in[2];
    const float* bih0 = (const float*)d_in[3];
    const float* bhh0 = (const float*)d_in[4];
    const float* Wih1 = (const float*)d_in[5];
    const float* Whh1 = (const float*)d_in[6];
    const float* bih1 = (const float*)d_in[7];
    const float* bhh1 = (const float*)d_in[8];
    const float* Wfc  = (const float*)d_in[9];
    const float* bfc  = (const float*)d_in[10];
    float* out = (float*)d_out;

    if (ws_size >= WS_NEED) {
        _Float16* wsw = (_Float16*)d_ws;
        wcvt<<<dim3(64), dim3(256), 0, stream>>>(Whh1, wsw);
        lstm2_fused<1><<<dim3(NBLK), dim3(NTH), DYN_WG, stream>>>(
            x, Wih0, Whh0, bih0, bhh0, Wih1, Whh1, bih1, bhh1, Wfc, bfc, out, wsw);
    } else {
        lstm2_fused<0><<<dim3(NBLK), dim3(NTH), DYN_LDSPAN, stream>>>(
            x, Wih0, Whh0, bih0, bhh0, Wih1, Whh1, bih1, bhh1, Wfc, bfc, out, nullptr);
    }
}

// Round 9
// 322.799 us; speedup vs baseline: 2.2859x; 2.2859x over previous
//
#include <hip/hip_runtime.h>

#define TSTEPS 128
#define NIN 24
#define HD 128
#define BT 16
#define NBLK 128     // 2048 / BT
#define NTH 1024     // 16 waves: 0-7 = layer-0 role, 8-15 = layer-1 role

// LDS geometry (units: _Float16 elements)
// h panels: [batch 16][hidden 128], row stride RS=136 (16B-aligned rows).
#define RS    136
#define SLOT  (BT*RS)          // 2176
#define H1B   (2*SLOT)         // h1 double buffer after h0 double buffer
#define W1B   (4*SLOT)         // whh1 fragment panel: 8 groups * 16 frags * 512
#define SM_ELTS (W1B + 65536)  // 74240 f16
#define SM_BYTES (SM_ELTS*2)   // 148480 B (dynamic LDS, 1 block/CU)

typedef _Float16 half8  __attribute__((ext_vector_type(8)));
typedef _Float16 half4v __attribute__((ext_vector_type(4)));
typedef float    floatx4 __attribute__((ext_vector_type(4)));

__device__ __forceinline__ float sigf(float x) {
    return __builtin_amdgcn_rcpf(1.0f + __expf(-x));
}
__device__ __forceinline__ float tanh_f(float x) {
    return 1.0f - 2.0f * __builtin_amdgcn_rcpf(1.0f + __expf(2.0f * x));
}

__device__ __forceinline__ half8 ldw8(const float* p) {
    const float4* q = (const float4*)p;
    float4 a = q[0], b = q[1];
    half8 r;
    r[0] = (_Float16)a.x; r[1] = (_Float16)a.y; r[2] = (_Float16)a.z; r[3] = (_Float16)a.w;
    r[4] = (_Float16)b.x; r[5] = (_Float16)b.y; r[6] = (_Float16)b.z; r[7] = (_Float16)b.w;
    return r;
}

// LDS-only barrier: drain own ds ops, sync, don't drain vmcnt (global x
// prefetch loads span barriers, T4-style).
__device__ __forceinline__ void barrier_lgkm() {
    asm volatile("s_waitcnt lgkmcnt(0)" ::: "memory");
    __builtin_amdgcn_s_barrier();
    __builtin_amdgcn_sched_barrier(0);
}

// =====================================================================
// Fused 2-layer LSTM, one block per 16-row batch tile, wave-role split:
//   waves 0-7  : layer 0 (wih0+whh0 in regs; bias folded via const-1 x col)
//   waves 8-15 : layer 1 (wih1 in regs; whh1 streamed from the LDS
//                fragment panel — register arithmetic forces streaming
//                exactly half the L1 weights: 2048-reg pool / 16 waves
//                = 128/wave; wih1+whh1 = 128 regs of weights alone)
// One-lag fusion: iter t computes layer0 step t and layer1 step t-1 off
// a single barrier (130 barrier arrivals per wave, uniform).
// Transposed MFMA orientation (A=weights, B=h^T): lane (qd,nn) holds gate
// rows hw*16+qd*4+r, batch col nn; h-write is one contiguous ds_write_b64.
// ASYMMETRIC PRIORITY (this round's delta vs the verified 263 us round-6
// kernel): only L1 waves (the long pole: 24 LDS reads + 32 MFMAs vs L0's
// 4 + 20) raise s_setprio around their read+MFMA cluster; L0 stays at 0
// so the scheduler genuinely favors the pole.
// =====================================================================
__global__ __launch_bounds__(NTH, 4)
void lstm2_fused(const float* __restrict__ x,
                 const float* __restrict__ Wih0, const float* __restrict__ Whh0,
                 const float* __restrict__ bih0, const float* __restrict__ bhh0,
                 const float* __restrict__ Wih1, const float* __restrict__ Whh1,
                 const float* __restrict__ bih1, const float* __restrict__ bhh1,
                 const float* __restrict__ Wfc,  const float* __restrict__ bfc,
                 float* __restrict__ out)
{
    extern __shared__ __align__(16) _Float16 SM[];

    const int tid = threadIdx.x;
    const int blk = blockIdx.x;
    const int wv  = tid >> 6;
    const int ln  = tid & 63;
    const int qd  = ln >> 4;
    const int nn  = ln & 15;
    const int b0  = blk * BT;

    const half8 z8 = {0, 0, 0, 0, 0, 0, 0, 0};
    const floatx4 zf4 = {0.f, 0.f, 0.f, 0.f};

    // ---- common prologue: zero h panels, stage whh1 panel (all 16 waves) ----
    for (int i = tid * 8; i < W1B; i += NTH * 8) *(half8*)&SM[i] = z8;
    // whh1 -> LDS in MFMA A-fragment order:
    // frag (hw_,tI,kk) at W1B + (hw_*16 + tI*4 + kk)*512 + (qd*16+nn)*8 + e
    for (int i = tid; i < 512 * 32; i += NTH) {
        int g  = i >> 5;
        int k0 = (i & 31) << 2;
        float4 v = *(const float4*)(Whh1 + g * HD + k0);
        half4v h; h[0] = (_Float16)v.x; h[1] = (_Float16)v.y;
                  h[2] = (_Float16)v.z; h[3] = (_Float16)v.w;
        int dst = W1B + ((((g >> 4) & 7) * 16) + (g >> 7) * 4 + (k0 >> 5)) * 512
                      + (((k0 >> 3) & 3) * 16 + (g & 15)) * 8 + (k0 & 7);
        *(half4v*)&SM[dst] = h;
    }

    if (wv < 8) {
        // ================= ROLE L0: layer 0, hidden cols wv*16..+16 =================
        const int hw_  = wv;
        const int hcol = hw_ * 16 + qd * 4;

        half8 wih0[4];           // bias folded at qd==3 via constant-1 x col
        half8 whh0[4][4];
#pragma unroll
        for (int tI = 0; tI < 4; ++tI) {
            int g = tI * HD + hw_ * 16 + nn;
            if (qd < 3) {
                wih0[tI] = ldw8(Wih0 + g * NIN + qd * 8);
            } else {
                wih0[tI] = z8;
                wih0[tI][0] = (_Float16)(bih0[g] + bhh0[g]);
            }
#pragma unroll
            for (int kk = 0; kk < 4; ++kk)
                whh0[tI][kk] = ldw8(Whh0 + g * HD + kk * 32 + qd * 8);
        }

        const float* xrow = x + (size_t)(b0 + nn) * (TSTEPS * NIN) + (qd < 3 ? qd * 8 : 0);
        float4 pf0 = *(const float4*)(xrow);
        float4 pf1 = *(const float4*)(xrow + 4);

        float cs0[4] = {0.f, 0.f, 0.f, 0.f};

        __syncthreads();   // barrier #0: zeros + whh1 panel staged

        // ---- iter 0: h0[0] (h0[-1]=0 -> only x MFMA) ----
        {
            half8 ax;
            if (qd < 3) {
                ax[0] = (_Float16)pf0.x; ax[1] = (_Float16)pf0.y; ax[2] = (_Float16)pf0.z; ax[3] = (_Float16)pf0.w;
                ax[4] = (_Float16)pf1.x; ax[5] = (_Float16)pf1.y; ax[6] = (_Float16)pf1.z; ax[7] = (_Float16)pf1.w;
            } else {
                ax = z8; ax[0] = (_Float16)1.0f;
            }
            pf0 = *(const float4*)(xrow + NIN);
            pf1 = *(const float4*)(xrow + NIN + 4);

            floatx4 acc0[4];
#pragma unroll
            for (int tI = 0; tI < 4; ++tI)
                acc0[tI] = __builtin_amdgcn_mfma_f32_16x16x32_f16(wih0[tI], ax, zf4, 0, 0, 0);

            half4v hw;
#pragma unroll
            for (int r = 0; r < 4; ++r) {
                float iv = sigf(acc0[0][r]);
                float gv = tanh_f(acc0[2][r]);
                float ov = sigf(acc0[3][r]);
                float cn = iv * gv;
                cs0[r] = cn;
                hw[r] = (_Float16)(ov * tanh_f(cn));
            }
            *(half4v*)&SM[0 * SLOT + nn * RS + hcol] = hw;   // h0[0] -> slot 0
        }

#pragma unroll 1
        for (int t = 1; t < TSTEPS; ++t) {
            barrier_lgkm();   // barrier #t

            half8 ax;
            if (qd < 3) {
                ax[0] = (_Float16)pf0.x; ax[1] = (_Float16)pf0.y; ax[2] = (_Float16)pf0.z; ax[3] = (_Float16)pf0.w;
                ax[4] = (_Float16)pf1.x; ax[5] = (_Float16)pf1.y; ax[6] = (_Float16)pf1.z; ax[7] = (_Float16)pf1.w;
            } else {
                ax = z8; ax[0] = (_Float16)1.0f;
            }
            {
                const int tn = (t < TSTEPS - 1) ? t + 1 : TSTEPS - 1;
                pf0 = *(const float4*)(xrow + (size_t)tn * NIN);
                pf1 = *(const float4*)(xrow + (size_t)tn * NIN + 4);
            }

            const int h0r = ((t - 1) & 1) * SLOT;
            const int h0w = (t & 1) * SLOT;

            floatx4 acc0[4];
#pragma unroll
            for (int tI = 0; tI < 4; ++tI)
                acc0[tI] = __builtin_amdgcn_mfma_f32_16x16x32_f16(wih0[tI], ax, zf4, 0, 0, 0);

            // no setprio here: L0 is the light role; keep it at prio 0 so the
            // scheduler favors the L1 pole (asymmetric-T5).
#pragma unroll
            for (int kk = 0; kk < 4; ++kk) {
                const half8 ah = *(const half8*)&SM[h0r + nn * RS + kk * 32 + qd * 8];
#pragma unroll
                for (int tI = 0; tI < 4; ++tI)
                    acc0[tI] = __builtin_amdgcn_mfma_f32_16x16x32_f16(whh0[tI][kk], ah, acc0[tI], 0, 0, 0);
            }

            half4v hw;
#pragma unroll
            for (int r = 0; r < 4; ++r) {
                float iv = sigf(acc0[0][r]);
                float fv = sigf(acc0[1][r]);
                float gv = tanh_f(acc0[2][r]);
                float ov = sigf(acc0[3][r]);
                float cn = fv * cs0[r] + iv * gv;
                cs0[r] = cn;
                hw[r] = (_Float16)(ov * tanh_f(cn));
            }
            *(half4v*)&SM[h0w + nn * RS + hcol] = hw;
        }

        barrier_lgkm();   // barrier #128 (publishes h0[127])
        barrier_lgkm();   // barrier #129 (waits for L1's h1[127])
    } else {
        // ================= ROLE L1: layer 1, hidden cols (wv-8)*16..+16 =================
        const int hw_  = wv - 8;
        const int hcol = hw_ * 16 + qd * 4;

        floatx4 bias1[4];
        half8 wih1[4][4];
#pragma unroll
        for (int tI = 0; tI < 4; ++tI) {
#pragma unroll
            for (int r = 0; r < 4; ++r)
                bias1[tI][r] = bih1[tI * HD + hcol + r] + bhh1[tI * HD + hcol + r];
            int g = tI * HD + hw_ * 16 + nn;
#pragma unroll
            for (int kk = 0; kk < 4; ++kk)
                wih1[tI][kk] = ldw8(Wih1 + g * HD + kk * 32 + qd * 8);
        }
        const int w1base = W1B + hw_ * 8192 + ln * 8;

        float cs1[4] = {0.f, 0.f, 0.f, 0.f};

        __syncthreads();   // barrier #0

        // loop t = 1..127 computes h1[t-1]
#pragma unroll 1
        for (int t = 1; t < TSTEPS; ++t) {
            barrier_lgkm();   // barrier #t: h0[t-1], h1[t-2] visible

            const int h0r = ((t - 1) & 1) * SLOT;
            const int h1r = H1B + (t & 1) * SLOT;            // h1[t-2]
            const int h1w = H1B + ((t & 1) ^ 1) * SLOT;      // h1[t-1]

            floatx4 acc1[4];
#pragma unroll
            for (int tI = 0; tI < 4; ++tI) acc1[tI] = bias1[tI];

            __builtin_amdgcn_s_setprio(1);   // L1 = long pole: elevated through reads+MFMA
#pragma unroll
            for (int kk = 0; kk < 4; ++kk) {
                const half8 ah = *(const half8*)&SM[h0r + nn * RS + kk * 32 + qd * 8];
#pragma unroll
                for (int tI = 0; tI < 4; ++tI)
                    acc1[tI] = __builtin_amdgcn_mfma_f32_16x16x32_f16(wih1[tI][kk], ah, acc1[tI], 0, 0, 0);
            }
#pragma unroll
            for (int kk = 0; kk < 4; ++kk) {
                const half8 a2 = *(const half8*)&SM[h1r + nn * RS + kk * 32 + qd * 8];
#pragma unroll
                for (int tI = 0; tI < 4; ++tI) {
                    const half8 w1 = *(const half8*)&SM[w1base + (tI * 4 + kk) * 512];
                    acc1[tI] = __builtin_amdgcn_mfma_f32_16x16x32_f16(w1, a2, acc1[tI], 0, 0, 0);
                }
            }
            __builtin_amdgcn_s_setprio(0);

            half4v hw;
#pragma unroll
            for (int r = 0; r < 4; ++r) {
                float iv = sigf(acc1[0][r]);
                float fv = sigf(acc1[1][r]);
                float gv = tanh_f(acc1[2][r]);
                float ov = sigf(acc1[3][r]);
                float cn = fv * cs1[r] + iv * gv;
                cs1[r] = cn;
                hw[r] = (_Float16)(ov * tanh_f(cn));
            }
            *(half4v*)&SM[h1w + nn * RS + hcol] = hw;
        }

        barrier_lgkm();   // barrier #128: h0[127] visible
        {
            // ---- epilogue: h1[127] from h0[127] (slot 1) + h1[126] (slot 0) ----
            floatx4 acc1[4];
#pragma unroll
            for (int tI = 0; tI < 4; ++tI) acc1[tI] = bias1[tI];
#pragma unroll
            for (int kk = 0; kk < 4; ++kk) {
                const half8 ah = *(const half8*)&SM[SLOT + nn * RS + kk * 32 + qd * 8];
#pragma unroll
                for (int tI = 0; tI < 4; ++tI)
                    acc1[tI] = __builtin_amdgcn_mfma_f32_16x16x32_f16(wih1[tI][kk], ah, acc1[tI], 0, 0, 0);
            }
#pragma unroll
            for (int kk = 0; kk < 4; ++kk) {
                const half8 a2 = *(const half8*)&SM[H1B + nn * RS + kk * 32 + qd * 8];
#pragma unroll
                for (int tI = 0; tI < 4; ++tI) {
                    const half8 w1 = *(const half8*)&SM[w1base + (tI * 4 + kk) * 512];
                    acc1[tI] = __builtin_amdgcn_mfma_f32_16x16x32_f16(w1, a2, acc1[tI], 0, 0, 0);
                }
            }
            half4v hw;
#pragma unroll
            for (int r = 0; r < 4; ++r) {
                float iv = sigf(acc1[0][r]);
                float fv = sigf(acc1[1][r]);
                float gv = tanh_f(acc1[2][r]);
                float ov = sigf(acc1[3][r]);
                float cn = fv * cs1[r] + iv * gv;
                hw[r] = (_Float16)(ov * tanh_f(cn));
            }
            *(half4v*)&SM[H1B + SLOT + nn * RS + hcol] = hw;   // h1[127] -> slot 1
        }
        barrier_lgkm();   // barrier #129: publish h1[127]
    }

    // =============== FC head: h1[127] in h1 slot 1 (first 512 threads) ===============
    if (tid < 512) {
        int b = tid >> 5, sub = tid & 31;
        const _Float16* hp = &SM[H1B + SLOT + b * RS + sub * 4];
        const float4 wv4 = *(const float4*)(Wfc + sub * 4);
        float s = (float)hp[0] * wv4.x + (float)hp[1] * wv4.y
                + (float)hp[2] * wv4.z + (float)hp[3] * wv4.w;
        s += __shfl_down(s, 16, 32);
        s += __shfl_down(s, 8, 32);
        s += __shfl_down(s, 4, 32);
        s += __shfl_down(s, 2, 32);
        s += __shfl_down(s, 1, 32);
        if (sub == 0) out[b0 + b] = s + bfc[0];
    }
}

extern "C" void kernel_launch(void* const* d_in, const int* in_sizes, int n_in,
                              void* d_out, int out_size, void* d_ws, size_t ws_size,
                              hipStream_t stream) {
    static bool attr_set = false;
    if (!attr_set) {
        hipFuncSetAttribute(reinterpret_cast<const void*>(&lstm2_fused),
                            hipFuncAttributeMaxDynamicSharedMemorySize, SM_BYTES);
        attr_set = true;
    }
    const float* x    = (const float*)d_in[0];
    const float* Wih0 = (const float*)d_in[1];
    const float* Whh0 = (const float*)d_in[2];
    const float* bih0 = (const float*)d_in[3];
    const float* bhh0 = (const float*)d_in[4];
    const float* Wih1 = (const float*)d_in[5];
    const float* Whh1 = (const float*)d_in[6];
    const float* bih1 = (const float*)d_in[7];
    const float* bhh1 = (const float*)d_in[8];
    const float* Wfc  = (const float*)d_in[9];
    const float* bfc  = (const float*)d_in[10];
    float* out = (float*)d_out;

    lstm2_fused<<<dim3(NBLK), dim3(NTH), SM_BYTES, stream>>>(
        x, Wih0, Whh0, bih0, bhh0, Wih1, Whh1, bih1, bhh1, Wfc, bfc, out);
}

// Round 10
// 320.076 us; speedup vs baseline: 2.3053x; 1.0085x over previous
//
#include <hip/hip_runtime.h>

#define TSTEPS 128
#define NIN 24
#define HD 128
#define BT 16
#define NBLK 128     // 2048 / BT
#define NTH 1024     // 16 waves: 0-7 = layer-0 role, 8-15 = layer-1 role

// LDS geometry (units: _Float16 elements)
// h panels: [batch 16][hidden 128], row stride RS=136 (16B-aligned rows,
// 17 16B-units/row == 1 mod 8 -> rows rotate across bank groups; reads are
// 2-way-aliased only, which is free on CDNA4).
#define RS    136
#define SLOT  (BT*RS)          // 2176
#define H1B   (2*SLOT)         // h1 double buffer after h0 double buffer
#define W1B   (4*SLOT)         // whh1 fragment panel: 8 groups * 16 frags * 512
#define SM_ELTS (W1B + 65536)  // 74240 f16
#define SM_BYTES (SM_ELTS*2)   // 148480 B (dynamic LDS, 1 block/CU)

typedef _Float16 half8  __attribute__((ext_vector_type(8)));
typedef _Float16 half4v __attribute__((ext_vector_type(4)));
typedef float    floatx4 __attribute__((ext_vector_type(4)));

__device__ __forceinline__ float sigf(float x) {
    return __builtin_amdgcn_rcpf(1.0f + __expf(-x));
}
__device__ __forceinline__ float tanh_f(float x) {
    return 1.0f - 2.0f * __builtin_amdgcn_rcpf(1.0f + __expf(2.0f * x));
}

__device__ __forceinline__ half8 ldw8(const float* p) {
    const float4* q = (const float4*)p;
    float4 a = q[0], b = q[1];
    half8 r;
    r[0] = (_Float16)a.x; r[1] = (_Float16)a.y; r[2] = (_Float16)a.z; r[3] = (_Float16)a.w;
    r[4] = (_Float16)b.x; r[5] = (_Float16)b.y; r[6] = (_Float16)b.z; r[7] = (_Float16)b.w;
    return r;
}

// LDS-only barrier: drain own ds ops, sync, don't drain vmcnt (global x
// prefetch loads span barriers, T4-style).
__device__ __forceinline__ void barrier_lgkm() {
    asm volatile("s_waitcnt lgkmcnt(0)" ::: "memory");
    __builtin_amdgcn_s_barrier();
    __builtin_amdgcn_sched_barrier(0);
}

// =====================================================================
// Fused 2-layer LSTM — FINAL configuration (verified best: 263 us steady).
// One block per 16-row batch tile, wave-role split:
//   waves 0-7  : layer 0 (wih0+whh0 in regs; bias folded via const-1 x col)
//   waves 8-15 : layer 1 (wih1+bias1 in regs; whh1 streamed from the LDS
//                fragment panel)
// Register wall (measured closed): unified arch+AGPR budget/wave at 16
// waves/CU = 2048/16 = 128; L1 weights alone are 128 regs/wave, so exactly
// half must stream from LDS. All alternatives measured worse:
//   whh1-in-regs -> 50 MB spill (R4); whh1-from-global -> latency on the
//   recurrent path (R8); cross-block pipelining -> fence cost (R2/R3);
//   lag-2 phase split -> no work moved (R7); asym-prio -> neutral (R9).
// One-lag fusion: iter t computes layer0 step t and layer1 step t-1 off a
// single lgkm-only barrier (130 arrivals/wave, uniform across roles).
// Transposed MFMA orientation (A=weights, B=h^T): lane (qd,nn) holds gate
// rows hw*16+qd*4+r, batch col nn; h-write is one contiguous ds_write_b64.
// Symmetric s_setprio(1) around both roles' read+MFMA clusters (verified
// best vs asymmetric).
// =====================================================================
__global__ __launch_bounds__(NTH, 4)
void lstm2_fused(const float* __restrict__ x,
                 const float* __restrict__ Wih0, const float* __restrict__ Whh0,
                 const float* __restrict__ bih0, const float* __restrict__ bhh0,
                 const float* __restrict__ Wih1, const float* __restrict__ Whh1,
                 const float* __restrict__ bih1, const float* __restrict__ bhh1,
                 const float* __restrict__ Wfc,  const float* __restrict__ bfc,
                 float* __restrict__ out)
{
    extern __shared__ __align__(16) _Float16 SM[];

    const int tid = threadIdx.x;
    const int blk = blockIdx.x;
    const int wv  = tid >> 6;
    const int ln  = tid & 63;
    const int qd  = ln >> 4;
    const int nn  = ln & 15;
    const int b0  = blk * BT;

    const half8 z8 = {0, 0, 0, 0, 0, 0, 0, 0};
    const floatx4 zf4 = {0.f, 0.f, 0.f, 0.f};

    // ---- common prologue: zero h panels, stage whh1 panel (all 16 waves) ----
    for (int i = tid * 8; i < W1B; i += NTH * 8) *(half8*)&SM[i] = z8;
    // whh1 -> LDS in MFMA A-fragment order:
    // frag (hw_,tI,kk) at W1B + (hw_*16 + tI*4 + kk)*512 + (qd*16+nn)*8 + e
    for (int i = tid; i < 512 * 32; i += NTH) {
        int g  = i >> 5;
        int k0 = (i & 31) << 2;
        float4 v = *(const float4*)(Whh1 + g * HD + k0);
        half4v h; h[0] = (_Float16)v.x; h[1] = (_Float16)v.y;
                  h[2] = (_Float16)v.z; h[3] = (_Float16)v.w;
        int dst = W1B + ((((g >> 4) & 7) * 16) + (g >> 7) * 4 + (k0 >> 5)) * 512
                      + (((k0 >> 3) & 3) * 16 + (g & 15)) * 8 + (k0 & 7);
        *(half4v*)&SM[dst] = h;
    }

    if (wv < 8) {
        // ================= ROLE L0: layer 0, hidden cols wv*16..+16 =================
        const int hw_  = wv;
        const int hcol = hw_ * 16 + qd * 4;

        half8 wih0[4];           // bias folded at qd==3 via constant-1 x col
        half8 whh0[4][4];
#pragma unroll
        for (int tI = 0; tI < 4; ++tI) {
            int g = tI * HD + hw_ * 16 + nn;
            if (qd < 3) {
                wih0[tI] = ldw8(Wih0 + g * NIN + qd * 8);
            } else {
                wih0[tI] = z8;
                wih0[tI][0] = (_Float16)(bih0[g] + bhh0[g]);
            }
#pragma unroll
            for (int kk = 0; kk < 4; ++kk)
                whh0[tI][kk] = ldw8(Whh0 + g * HD + kk * 32 + qd * 8);
        }

        const float* xrow = x + (size_t)(b0 + nn) * (TSTEPS * NIN) + (qd < 3 ? qd * 8 : 0);
        float4 pf0 = *(const float4*)(xrow);
        float4 pf1 = *(const float4*)(xrow + 4);

        float cs0[4] = {0.f, 0.f, 0.f, 0.f};

        __syncthreads();   // barrier #0: zeros + whh1 panel staged

        // ---- iter 0: h0[0] (h0[-1]=0 -> only x MFMA) ----
        {
            half8 ax;
            if (qd < 3) {
                ax[0] = (_Float16)pf0.x; ax[1] = (_Float16)pf0.y; ax[2] = (_Float16)pf0.z; ax[3] = (_Float16)pf0.w;
                ax[4] = (_Float16)pf1.x; ax[5] = (_Float16)pf1.y; ax[6] = (_Float16)pf1.z; ax[7] = (_Float16)pf1.w;
            } else {
                ax = z8; ax[0] = (_Float16)1.0f;
            }
            pf0 = *(const float4*)(xrow + NIN);
            pf1 = *(const float4*)(xrow + NIN + 4);

            floatx4 acc0[4];
#pragma unroll
            for (int tI = 0; tI < 4; ++tI)
                acc0[tI] = __builtin_amdgcn_mfma_f32_16x16x32_f16(wih0[tI], ax, zf4, 0, 0, 0);

            half4v hw;
#pragma unroll
            for (int r = 0; r < 4; ++r) {
                float iv = sigf(acc0[0][r]);
                float gv = tanh_f(acc0[2][r]);
                float ov = sigf(acc0[3][r]);
                float cn = iv * gv;
                cs0[r] = cn;
                hw[r] = (_Float16)(ov * tanh_f(cn));
            }
            *(half4v*)&SM[0 * SLOT + nn * RS + hcol] = hw;   // h0[0] -> slot 0
        }

#pragma unroll 1
        for (int t = 1; t < TSTEPS; ++t) {
            barrier_lgkm();   // barrier #t

            half8 ax;
            if (qd < 3) {
                ax[0] = (_Float16)pf0.x; ax[1] = (_Float16)pf0.y; ax[2] = (_Float16)pf0.z; ax[3] = (_Float16)pf0.w;
                ax[4] = (_Float16)pf1.x; ax[5] = (_Float16)pf1.y; ax[6] = (_Float16)pf1.z; ax[7] = (_Float16)pf1.w;
            } else {
                ax = z8; ax[0] = (_Float16)1.0f;
            }
            {
                const int tn = (t < TSTEPS - 1) ? t + 1 : TSTEPS - 1;
                pf0 = *(const float4*)(xrow + (size_t)tn * NIN);
                pf1 = *(const float4*)(xrow + (size_t)tn * NIN + 4);
            }

            const int h0r = ((t - 1) & 1) * SLOT;
            const int h0w = (t & 1) * SLOT;

            floatx4 acc0[4];
#pragma unroll
            for (int tI = 0; tI < 4; ++tI)
                acc0[tI] = __builtin_amdgcn_mfma_f32_16x16x32_f16(wih0[tI], ax, zf4, 0, 0, 0);

            __builtin_amdgcn_s_setprio(1);
#pragma unroll
            for (int kk = 0; kk < 4; ++kk) {
                const half8 ah = *(const half8*)&SM[h0r + nn * RS + kk * 32 + qd * 8];
#pragma unroll
                for (int tI = 0; tI < 4; ++tI)
                    acc0[tI] = __builtin_amdgcn_mfma_f32_16x16x32_f16(whh0[tI][kk], ah, acc0[tI], 0, 0, 0);
            }
            __builtin_amdgcn_s_setprio(0);

            half4v hw;
#pragma unroll
            for (int r = 0; r < 4; ++r) {
                float iv = sigf(acc0[0][r]);
                float fv = sigf(acc0[1][r]);
                float gv = tanh_f(acc0[2][r]);
                float ov = sigf(acc0[3][r]);
                float cn = fv * cs0[r] + iv * gv;
                cs0[r] = cn;
                hw[r] = (_Float16)(ov * tanh_f(cn));
            }
            *(half4v*)&SM[h0w + nn * RS + hcol] = hw;
        }

        barrier_lgkm();   // barrier #128 (publishes h0[127])
        barrier_lgkm();   // barrier #129 (waits for L1's h1[127])
    } else {
        // ================= ROLE L1: layer 1, hidden cols (wv-8)*16..+16 =================
        const int hw_  = wv - 8;
        const int hcol = hw_ * 16 + qd * 4;

        floatx4 bias1[4];
        half8 wih1[4][4];
#pragma unroll
        for (int tI = 0; tI < 4; ++tI) {
#pragma unroll
            for (int r = 0; r < 4; ++r)
                bias1[tI][r] = bih1[tI * HD + hcol + r] + bhh1[tI * HD + hcol + r];
            int g = tI * HD + hw_ * 16 + nn;
#pragma unroll
            for (int kk = 0; kk < 4; ++kk)
                wih1[tI][kk] = ldw8(Wih1 + g * HD + kk * 32 + qd * 8);
        }
        const int w1base = W1B + hw_ * 8192 + ln * 8;

        float cs1[4] = {0.f, 0.f, 0.f, 0.f};

        __syncthreads();   // barrier #0

        // loop t = 1..127 computes h1[t-1]
#pragma unroll 1
        for (int t = 1; t < TSTEPS; ++t) {
            barrier_lgkm();   // barrier #t: h0[t-1], h1[t-2] visible

            const int h0r = ((t - 1) & 1) * SLOT;
            const int h1r = H1B + (t & 1) * SLOT;            // h1[t-2]
            const int h1w = H1B + ((t & 1) ^ 1) * SLOT;      // h1[t-1]

            floatx4 acc1[4];
#pragma unroll
            for (int tI = 0; tI < 4; ++tI) acc1[tI] = bias1[tI];

            __builtin_amdgcn_s_setprio(1);
#pragma unroll
            for (int kk = 0; kk < 4; ++kk) {
                const half8 ah = *(const half8*)&SM[h0r + nn * RS + kk * 32 + qd * 8];
#pragma unroll
                for (int tI = 0; tI < 4; ++tI)
                    acc1[tI] = __builtin_amdgcn_mfma_f32_16x16x32_f16(wih1[tI][kk], ah, acc1[tI], 0, 0, 0);
            }
#pragma unroll
            for (int kk = 0; kk < 4; ++kk) {
                const half8 a2 = *(const half8*)&SM[h1r + nn * RS + kk * 32 + qd * 8];
#pragma unroll
                for (int tI = 0; tI < 4; ++tI) {
                    const half8 w1 = *(const half8*)&SM[w1base + (tI * 4 + kk) * 512];
                    acc1[tI] = __builtin_amdgcn_mfma_f32_16x16x32_f16(w1, a2, acc1[tI], 0, 0, 0);
                }
            }
            __builtin_amdgcn_s_setprio(0);

            half4v hw;
#pragma unroll
            for (int r = 0; r < 4; ++r) {
                float iv = sigf(acc1[0][r]);
                float fv = sigf(acc1[1][r]);
                float gv = tanh_f(acc1[2][r]);
                float ov = sigf(acc1[3][r]);
                float cn = fv * cs1[r] + iv * gv;
                cs1[r] = cn;
                hw[r] = (_Float16)(ov * tanh_f(cn));
            }
            *(half4v*)&SM[h1w + nn * RS + hcol] = hw;
        }

        barrier_lgkm();   // barrier #128: h0[127] visible
        {
            // ---- epilogue: h1[127] from h0[127] (slot 1) + h1[126] (slot 0) ----
            floatx4 acc1[4];
#pragma unroll
            for (int tI = 0; tI < 4; ++tI) acc1[tI] = bias1[tI];
#pragma unroll
            for (int kk = 0; kk < 4; ++kk) {
                const half8 ah = *(const half8*)&SM[SLOT + nn * RS + kk * 32 + qd * 8];
#pragma unroll
                for (int tI = 0; tI < 4; ++tI)
                    acc1[tI] = __builtin_amdgcn_mfma_f32_16x16x32_f16(wih1[tI][kk], ah, acc1[tI], 0, 0, 0);
            }
#pragma unroll
            for (int kk = 0; kk < 4; ++kk) {
                const half8 a2 = *(const half8*)&SM[H1B + nn * RS + kk * 32 + qd * 8];
#pragma unroll
                for (int tI = 0; tI < 4; ++tI) {
                    const half8 w1 = *(const half8*)&SM[w1base + (tI * 4 + kk) * 512];
                    acc1[tI] = __builtin_amdgcn_mfma_f32_16x16x32_f16(w1, a2, acc1[tI], 0, 0, 0);
                }
            }
            half4v hw;
#pragma unroll
            for (int r = 0; r < 4; ++r) {
                float iv = sigf(acc1[0][r]);
                float fv = sigf(acc1[1][r]);
                float gv = tanh_f(acc1[2][r]);
                float ov = sigf(acc1[3][r]);
                float cn = fv * cs1[r] + iv * gv;
                hw[r] = (_Float16)(ov * tanh_f(cn));
            }
            *(half4v*)&SM[H1B + SLOT + nn * RS + hcol] = hw;   // h1[127] -> slot 1
        }
        barrier_lgkm();   // barrier #129: publish h1[127]
    }

    // =============== FC head: h1[127] in h1 slot 1 (first 512 threads) ===============
    if (tid < 512) {
        int b = tid >> 5, sub = tid & 31;
        const _Float16* hp = &SM[H1B + SLOT + b * RS + sub * 4];
        const float4 wv4 = *(const float4*)(Wfc + sub * 4);
        float s = (float)hp[0] * wv4.x + (float)hp[1] * wv4.y
                + (float)hp[2] * wv4.z + (float)hp[3] * wv4.w;
        s += __shfl_down(s, 16, 32);
        s += __shfl_down(s, 8, 32);
        s += __shfl_down(s, 4, 32);
        s += __shfl_down(s, 2, 32);
        s += __shfl_down(s, 1, 32);
        if (sub == 0) out[b0 + b] = s + bfc[0];
    }
}

extern "C" void kernel_launch(void* const* d_in, const int* in_sizes, int n_in,
                              void* d_out, int out_size, void* d_ws, size_t ws_size,
                              hipStream_t stream) {
    static bool attr_set = false;
    if (!attr_set) {
        hipFuncSetAttribute(reinterpret_cast<const void*>(&lstm2_fused),
                            hipFuncAttributeMaxDynamicSharedMemorySize, SM_BYTES);
        attr_set = true;
    }
    const float* x    = (const float*)d_in[0];
    const float* Wih0 = (const float*)d_in[1];
    const float* Whh0 = (const float*)d_in[2];
    const float* bih0 = (const float*)d_in[3];
    const float* bhh0 = (const float*)d_in[4];
    const float* Wih1 = (const float*)d_in[5];
    const float* Whh1 = (const float*)d_in[6];
    const float* bih1 = (const float*)d_in[7];
    const float* bhh1 = (const float*)d_in[8];
    const float* Wfc  = (const float*)d_in[9];
    const float* bfc  = (const float*)d_in[10];
    float* out = (float*)d_out;

    lstm2_fused<<<dim3(NBLK), dim3(NTH), SM_BYTES, stream>>>(
        x, Wih0, Whh0, bih0, bhh0, Wih1, Whh1, bih1, bhh1, Wfc, bfc, out);
}